// Round 16
// baseline (323.056 us; speedup 1.0000x reference)
//
#include <hip/hip_runtime.h>

typedef _Float16 f16;
typedef f16 f16x2 __attribute__((ext_vector_type(2)));
typedef f16 f16x8 __attribute__((ext_vector_type(8)));
typedef __fp16 h2v __attribute__((ext_vector_type(2)));
typedef float f32x4 __attribute__((ext_vector_type(4)));
typedef float f32x16 __attribute__((ext_vector_type(16)));
typedef unsigned int uint;

#define NCH 16
#define NB 32
#define NH 256
#define NW 256
#define HW 65536
#define CHW 1048576

// weight image (f16 A-frags + f32 bias frags): f16x8 idx WF1=0, WF2=1024, WF3=3072, WF4=5120
#define BIAS_BYTE 90112
#define WS_BYTES 91648   // LDS holds ONLY this now

__global__ void prep_k(const float* __restrict__ w1, const float* __restrict__ w2,
                       const float* __restrict__ w3, const float* __restrict__ w4,
                       const float* __restrict__ b1, const float* __restrict__ b2,
                       const float* __restrict__ b3, float* __restrict__ wsf) {
  f16* wf = (f16*)wsf;
  int id = blockIdx.x * 256 + threadIdx.x;
  if (id < 8192) {
    int j = id & 7, l = (id >> 3) & 63, mt = (id >> 9) & 3, kt = id >> 11;
    int o = mt * 32 + (l & 31), c = kt * 16 + (l >> 5) * 8 + j;
    wf[id] = (f16)w1[o * 64 + c];
  } else if (id < 24576) {
    int t = id - 8192;
    int j = t & 7, l = (t >> 3) & 63, mt = (t >> 9) & 3, kt = t >> 11;
    int o = mt * 32 + (l & 31), c = kt * 16 + (l >> 5) * 8 + j;
    wf[8192 + t] = (f16)w2[o * 128 + c];
  } else if (id < 40960) {
    int t = id - 24576;
    int j = t & 7, l = (t >> 3) & 63, mt = (t >> 9) & 3, kt = t >> 11;
    int o = mt * 32 + (l & 31), c = kt * 16 + (l >> 5) * 8 + j;
    wf[24576 + t] = (f16)w3[o * 128 + c];
  } else if (id < 45056) {
    int t = id - 40960;
    int j = t & 7, l = (t >> 3) & 63, kt = t >> 9;
    int m = l & 31, hh = l >> 5;
    int c = kt * 16 + hh * 8 + j;
    wf[40960 + t] = (m < 16) ? (f16)w4[m * 128 + c] : (f16)0.f;
  } else if (id < 45440) {
    int t = id - 45056;
    int r = t & 15, hh = (t >> 4) & 1, mt = (t >> 5) & 3, ly = t >> 7;
    const float* bb = (ly == 0) ? b1 : (ly == 1) ? b2 : b3;
    ((float*)((unsigned char*)wsf + BIAS_BYTE))[t] =
        bb[mt * 32 + (r & 3) + 8 * (r >> 2) + 4 * hh];
  }
}

__device__ __forceinline__ void pl32swap(uint& a, uint& b) {
  asm volatile("v_permlane32_swap_b32 %0, %1" : "+v"(a), "+v"(b));
}

__device__ __forceinline__ f16x8 mk8(uint a, uint b, uint c, uint d) {
  union { uint u[4]; f16x8 v; } z;
  z.u[0] = a; z.u[1] = b; z.u[2] = c; z.u[3] = d;
  return z.v;
}

// Dual-half layer: one A-frag ds_read feeds BOTH halves' MFMAs (halves LDS A-traffic)
template <int NKT>
__device__ __forceinline__ void gemm2(const unsigned char* __restrict__ smem,
                                      int wfFragBase, int biasFloatOff, int lane, int hi,
                                      const f16x8* __restrict__ BL,
                                      const f16x8* __restrict__ BH,
                                      f32x16 accL[4], f32x16 accH[4]) {
#pragma unroll
  for (int mt = 0; mt < 4; ++mt) {
    const f32x16* bp =
        (const f32x16*)(smem + BIAS_BYTE + 4 * (biasFloatOff + (mt * 2 + hi) * 16));
    accL[mt] = *bp;
    accH[mt] = *bp;
  }
  const f16x8* A = (const f16x8*)smem + wfFragBase + lane;
  __builtin_amdgcn_s_setprio(1);
#pragma unroll
  for (int kt = 0; kt < NKT; ++kt) {
#pragma unroll
    for (int mt = 0; mt < 4; ++mt) {
      f16x8 a = A[(kt * 4 + mt) * 64];
      accL[mt] = __builtin_amdgcn_mfma_f32_32x32x16_f16(a, BL[kt], accL[mt], 0, 0, 0);
      accH[mt] = __builtin_amdgcn_mfma_f32_32x32x16_f16(a, BH[kt], accH[mt], 0, 0, 0);
    }
  }
  __builtin_amdgcn_s_setprio(0);
}

// lrelu in packed f16 (cvt_pkrtz + pk_mul + pk_max) -> permlane -> next B-frags
__device__ __forceinline__ void epilogue_swap(const f32x16 acc[4], f16x8 Bn[8]) {
  uint w[32];
  const h2v c001 = {(__fp16)0.01f, (__fp16)0.01f};
#pragma unroll
  for (int mt = 0; mt < 4; ++mt) {
#pragma unroll
    for (int i = 0; i < 8; ++i) {
      h2v u = __builtin_amdgcn_cvt_pkrtz(acc[mt][2 * i], acc[mt][2 * i + 1]);
      h2v s = u * c001;
      h2v m = __builtin_elementwise_max(u, s);
      w[mt * 8 + i] = __builtin_bit_cast(uint, m);
    }
  }
#pragma unroll
  for (int kt = 0; kt < 8; ++kt) {
    int mt = kt >> 1, sub = kt & 1;
    int W = mt * 8 + sub * 4;
    uint a0 = w[W], a1 = w[W + 1], a2 = w[W + 2], a3 = w[W + 3];
    pl32swap(a0, a2);
    pl32swap(a1, a3);
    Bn[kt] = mk8(a0, a1, a2, a3);
  }
}

// perception straight from global x (L2-hot), zero-padded borders.
// Lane covers 8 channels (hi-set) of its own pixel (row, col).
__device__ __forceinline__ void perc_g(const float* __restrict__ xb, int row, int col,
                                       int hi, f16x8 Bh[4]) {
  const bool rm = row > 0, rp = row < NH - 1;   // wave-uniform
  const bool cm = col > 0, cp = col < NW - 1;   // per-lane (edge lanes only)
  const int cl = cm ? col - 1 : col;
  const int cr = cp ? col + 1 : col;
  uint yw[16];
#pragma unroll
  for (int kt = 0; kt < 4; ++kt) {
#pragma unroll
    for (int cpair = 0; cpair < 2; ++cpair) {
      const int c = kt * 4 + hi * 2 + cpair;
      const float* pm = xb + ((size_t)c << 16) + ((size_t)row << 8);
      float v10 = pm[cl], v11 = pm[col], v12 = pm[cr];
      v10 = cm ? v10 : 0.f;
      v12 = cp ? v12 : 0.f;
      float v00 = 0.f, v01 = 0.f, v02 = 0.f, v20 = 0.f, v21 = 0.f, v22 = 0.f;
      if (rm) {
        const float* pt = pm - NW;
        float a = pt[cl], bq = pt[col], cq = pt[cr];
        v00 = cm ? a : 0.f;
        v01 = bq;
        v02 = cp ? cq : 0.f;
      }
      if (rp) {
        const float* pb = pm + NW;
        float a = pb[cl], bq = pb[col], cq = pb[cr];
        v20 = cm ? a : 0.f;
        v21 = bq;
        v22 = cp ? cq : 0.f;
      }
      float rs0 = v00 + v01 + v02, rs2 = v20 + v21 + v22;
      float fsx = (v02 - v00) + (v22 - v20) + 2.f * (v12 - v10);
      float fsy = (rs2 - rs0) + (v21 - v01);
      float flap = (rs0 + rs2 + v10 + v12) - 8.f * v11;
      h2v t0 = __builtin_amdgcn_cvt_pkrtz(v11, fsx);
      h2v t1 = __builtin_amdgcn_cvt_pkrtz(fsy, flap);
      yw[kt * 4 + cpair * 2 + 0] = __builtin_bit_cast(uint, t0);
      yw[kt * 4 + cpair * 2 + 1] = __builtin_bit_cast(uint, t1);
    }
  }
#pragma unroll
  for (int kt = 0; kt < 4; ++kt)
    Bh[kt] = mk8(yw[kt * 4], yw[kt * 4 + 1], yw[kt * 4 + 2], yw[kt * 4 + 3]);
}

__global__ __launch_bounds__(512, 2)
void nca_mlp_k(const float* __restrict__ x, const float* __restrict__ wsf,
               const float* __restrict__ mask, float* __restrict__ xn) {
  extern __shared__ unsigned char smem[];
  const int tid = threadIdx.x;
  const int lane = tid & 63;
  const int wv = tid >> 6;      // 0..7 = tile row
  const int pc = lane & 31;
  const int hi = lane >> 5;

  const int tile0 = blockIdx.x * 16;
  const int b = tile0 >> 7;                 // constant per block
  const float* xb = x + (size_t)b * CHW;
  float* xnb = xn + (size_t)b * CHW;
  const float* mb = mask + (size_t)b * HW;

  // ---- stage weights+bias once (linear b128 copy), sole barrier ----
  {
    const uint4* src = (const uint4*)wsf;
    uint4* dst = (uint4*)smem;
    for (int i = tid; i < WS_BYTES / 16; i += 512) dst[i] = src[i];
  }
  __syncthreads();

  // ---- free-running tile loop: no barriers, waves fully independent ----
  for (int t = 0; t < 16; ++t) {
    const int tile = tile0 + t;
    const int cx = tile & 3, ry = (tile >> 2) & 31;
    const int row = ry * 8 + wv;
    const int colL = cx * 64 + pc;
    const int colH = colL + 32;

    // ---- perception from global (both halves) ----
    f16x8 B1L[4], B1H[4];
    perc_g(xb, row, colL, hi, B1L);
    perc_g(xb, row, colH, hi, B1H);

    // ---- MLP chain (dual-half, shared A-reads) ----
    f32x16 accL[4], accH[4];
    f16x8 B2L[8], B2H[8], B3L[8], B3H[8], B4L[8], B4H[8];

    gemm2<4>(smem, 0, 0, lane, hi, B1L, B1H, accL, accH);
    epilogue_swap(accL, B2L);
    epilogue_swap(accH, B2H);
    gemm2<8>(smem, 1024, 128, lane, hi, B2L, B2H, accL, accH);
    epilogue_swap(accL, B3L);
    epilogue_swap(accH, B3H);
    gemm2<8>(smem, 3072, 256, lane, hi, B3L, B3H, accL, accH);
    epilogue_swap(accL, B4L);
    epilogue_swap(accH, B4H);

    f32x16 a4L, a4H;
#pragma unroll
    for (int r = 0; r < 16; ++r) { a4L[r] = 0.f; a4H[r] = 0.f; }
    {
      const f16x8* A4 = (const f16x8*)smem + 5120 + lane;
      __builtin_amdgcn_s_setprio(1);
#pragma unroll
      for (int kt = 0; kt < 8; ++kt) {
        f16x8 a = A4[kt * 64];
        a4L = __builtin_amdgcn_mfma_f32_32x32x16_f16(a, B4L[kt], a4L, 0, 0, 0);
        a4H = __builtin_amdgcn_mfma_f32_32x32x16_f16(a, B4H[kt], a4H, 0, 0, 0);
      }
      __builtin_amdgcn_s_setprio(0);
    }

    // ---- update: x_new = x + dy * mask (x re-read from global, L2-hot) ----
    {
      const float* xrb = xb + (row << 8);
      float* xob = xnb + (row << 8);
      const float* mrow = mb + (row << 8);
      {
        float mv = mrow[colL];
#pragma unroll
        for (int r = 0; r < 8; ++r) {
          int ch = (r & 3) + 8 * (r >> 2) + 4 * hi;
          xob[((size_t)ch << 16) + colL] = xrb[((size_t)ch << 16) + colL] + a4L[r] * mv;
        }
      }
      {
        float mv = mrow[colH];
#pragma unroll
        for (int r = 0; r < 8; ++r) {
          int ch = (r & 3) + 8 * (r >> 2) + 4 * hi;
          xob[((size_t)ch << 16) + colH] = xrb[((size_t)ch << 16) + colH] + a4H[r] * mv;
        }
      }
    }
  }
}

// alive factor: row-block with LDS horizontal-max sharing; zero dead pixels
__global__ void alive_scale_k(const float* __restrict__ x, float* __restrict__ xn) {
  __shared__ float pm[4][258];
  const int col = threadIdx.x;
  const int row = blockIdx.x;
  const int b = blockIdx.y;
  const float NEG = -3.0e38f;
  float v0 = NEG, v1 = NEG, v2 = NEG, v3 = NEG;
  const size_t base0 = (size_t)b * CHW + ((size_t)row << 8) + col;
#pragma unroll
  for (int dr = -1; dr <= 1; ++dr) {
    int rr = row + dr;
    if ((unsigned)rr < NH) {
      long o = (long)base0 + dr * NW;
      v0 = fmaxf(v0, x[o]);
      v1 = fmaxf(v1, x[o + HW]);
      v2 = fmaxf(v2, xn[o]);
      v3 = fmaxf(v3, xn[o + HW]);
    }
  }
  pm[0][col + 1] = v0;
  pm[1][col + 1] = v1;
  pm[2][col + 1] = v2;
  pm[3][col + 1] = v3;
  if (col == 0) {
#pragma unroll
    for (int f = 0; f < 4; ++f) { pm[f][0] = NEG; pm[f][257] = NEG; }
  }
  __syncthreads();
  float p0 = fmaxf(fmaxf(pm[0][col], pm[0][col + 1]), pm[0][col + 2]);
  float p1 = fmaxf(fmaxf(pm[1][col], pm[1][col + 1]), pm[1][col + 2]);
  float p2 = fmaxf(fmaxf(pm[2][col], pm[2][col + 1]), pm[2][col + 2]);
  float p3 = fmaxf(fmaxf(pm[3][col], pm[3][col + 1]), pm[3][col + 2]);
  bool alive = ((fabsf(p0) + fabsf(p1)) > 0.01f) && ((fabsf(p2) + fabsf(p3)) > 0.01f);
  if (!alive) {
#pragma unroll
    for (int ch = 0; ch < NCH; ++ch) xn[base0 + ((size_t)ch << 16)] = 0.f;
  }
}

extern "C" void kernel_launch(void* const* d_in, const int* in_sizes, int n_in,
                              void* d_out, int out_size, void* d_ws, size_t ws_size,
                              hipStream_t stream) {
  const float* x    = (const float*)d_in[0];
  const float* w1   = (const float*)d_in[1];
  const float* b1   = (const float*)d_in[2];
  const float* w2   = (const float*)d_in[3];
  const float* b2   = (const float*)d_in[4];
  const float* w3   = (const float*)d_in[5];
  const float* b3   = (const float*)d_in[6];
  const float* w4   = (const float*)d_in[7];
  const float* mask = (const float*)d_in[8];

  float* wsf = (float*)d_ws;
  float* xn = (float*)d_out;

  hipFuncSetAttribute(reinterpret_cast<const void*>(nca_mlp_k),
                      hipFuncAttributeMaxDynamicSharedMemorySize, WS_BYTES);

  prep_k<<<178, 256, 0, stream>>>(w1, w2, w3, w4, b1, b2, b3, wsf);
  nca_mlp_k<<<256, 512, WS_BYTES, stream>>>(x, wsf, mask, xn);
  alive_scale_k<<<dim3(NH, NB), 256, 0, stream>>>(x, xn);
}

// Round 17
// 312.929 us; speedup vs baseline: 1.0324x; 1.0324x over previous
//
#include <hip/hip_runtime.h>

typedef _Float16 f16;
typedef f16 f16x2 __attribute__((ext_vector_type(2)));
typedef f16 f16x8 __attribute__((ext_vector_type(8)));
typedef __fp16 h2v __attribute__((ext_vector_type(2)));
typedef float f32x4 __attribute__((ext_vector_type(4)));
typedef float f32x16 __attribute__((ext_vector_type(16)));
typedef unsigned int uint;
typedef unsigned short ushort;
typedef unsigned long long ull;

#define NCH 16
#define NB 32
#define NH 256
#define NW 256
#define HW 65536
#define CHW 1048576

// weight image (f16 A-frags + f32 bias frags): f16x8 idx WF1=0, WF2=1024, WF3=3072, WF4=5120
#define BIAS_BYTE 90112
#define WS_BYTES 91648
// x tile: f32 [ch16][rr10][cc66], staged by global_load_lds DMA
#define XT_OFF 91648
#define XT_FLOATS (16*10*66)
// active-pixel lists (double-buffered): 2 x 544 ushort + 2 x 512 flags + 2 ints
#define LISTS_OFF (XT_OFF + XT_FLOATS*4)       // 133888
#define FLAGS_OFF (LISTS_OFF + 2*544*2)        // +2176
#define NACT_OFF  (FLAGS_OFF + 2*512)          // +1024
#define LDS_TOTAL (NACT_OFF + 16)              // 137120

__global__ void prep_k(const float* __restrict__ w1, const float* __restrict__ w2,
                       const float* __restrict__ w3, const float* __restrict__ w4,
                       const float* __restrict__ b1, const float* __restrict__ b2,
                       const float* __restrict__ b3, float* __restrict__ wsf) {
  f16* wf = (f16*)wsf;
  int id = blockIdx.x * 256 + threadIdx.x;
  if (id < 8192) {
    int j = id & 7, l = (id >> 3) & 63, mt = (id >> 9) & 3, kt = id >> 11;
    int o = mt * 32 + (l & 31), c = kt * 16 + (l >> 5) * 8 + j;
    wf[id] = (f16)w1[o * 64 + c];
  } else if (id < 24576) {
    int t = id - 8192;
    int j = t & 7, l = (t >> 3) & 63, mt = (t >> 9) & 3, kt = t >> 11;
    int o = mt * 32 + (l & 31), c = kt * 16 + (l >> 5) * 8 + j;
    wf[8192 + t] = (f16)w2[o * 128 + c];
  } else if (id < 40960) {
    int t = id - 24576;
    int j = t & 7, l = (t >> 3) & 63, mt = (t >> 9) & 3, kt = t >> 11;
    int o = mt * 32 + (l & 31), c = kt * 16 + (l >> 5) * 8 + j;
    wf[24576 + t] = (f16)w3[o * 128 + c];
  } else if (id < 45056) {
    int t = id - 40960;
    int j = t & 7, l = (t >> 3) & 63, kt = t >> 9;
    int m = l & 31, hh = l >> 5;
    int c = kt * 16 + hh * 8 + j;
    wf[40960 + t] = (m < 16) ? (f16)w4[m * 128 + c] : (f16)0.f;
  } else if (id < 45440) {
    int t = id - 45056;
    int r = t & 15, hh = (t >> 4) & 1, mt = (t >> 5) & 3, ly = t >> 7;
    const float* bb = (ly == 0) ? b1 : (ly == 1) ? b2 : b3;
    ((float*)((unsigned char*)wsf + BIAS_BYTE))[t] =
        bb[mt * 32 + (r & 3) + 8 * (r >> 2) + 4 * hh];
  }
}

__device__ __forceinline__ void pl32swap(uint& a, uint& b) {
  asm volatile("v_permlane32_swap_b32 %0, %1" : "+v"(a), "+v"(b));
}

__device__ __forceinline__ f16x8 mk8(uint a, uint b, uint c, uint d) {
  union { uint u[4]; f16x8 v; } z;
  z.u[0] = a; z.u[1] = b; z.u[2] = c; z.u[3] = d;
  return z.v;
}

__device__ __forceinline__ void gload_lds4(const float* g, float* l) {
  __builtin_amdgcn_global_load_lds(
      (const __attribute__((address_space(1))) unsigned int*)(const void*)g,
      (__attribute__((address_space(3))) unsigned int*)(void*)l, 4, 0, 0);
}

// Single-half layer: bias init from LDS frags + MFMA cluster (R13-identical)
template <int NKT>
__device__ __forceinline__ void gemm_half(const unsigned char* __restrict__ smem,
                                          int wfFragBase, int biasFloatOff, int lane, int hi,
                                          const f16x8* __restrict__ B, f32x16 acc[4]) {
#pragma unroll
  for (int mt = 0; mt < 4; ++mt) {
    const f32x16* bp =
        (const f32x16*)(smem + BIAS_BYTE + 4 * (biasFloatOff + (mt * 2 + hi) * 16));
    acc[mt] = *bp;
  }
  const f16x8* A = (const f16x8*)smem + wfFragBase + lane;
  __builtin_amdgcn_s_setprio(1);
#pragma unroll
  for (int kt = 0; kt < NKT; ++kt) {
#pragma unroll
    for (int mt = 0; mt < 4; ++mt) {
      f16x8 a = A[(kt * 4 + mt) * 64];
      acc[mt] = __builtin_amdgcn_mfma_f32_32x32x16_f16(a, B[kt], acc[mt], 0, 0, 0);
    }
  }
  __builtin_amdgcn_s_setprio(0);
}

// lrelu in packed f16 -> permlane -> next B-frags (R13-identical)
__device__ __forceinline__ void epilogue_swap(const f32x16 acc[4], f16x8 Bn[8]) {
  uint w[32];
  const h2v c001 = {(__fp16)0.01f, (__fp16)0.01f};
#pragma unroll
  for (int mt = 0; mt < 4; ++mt) {
#pragma unroll
    for (int i = 0; i < 8; ++i) {
      h2v u = __builtin_amdgcn_cvt_pkrtz(acc[mt][2 * i], acc[mt][2 * i + 1]);
      h2v s = u * c001;
      h2v m = __builtin_elementwise_max(u, s);
      w[mt * 8 + i] = __builtin_bit_cast(uint, m);
    }
  }
#pragma unroll
  for (int kt = 0; kt < 8; ++kt) {
    int mt = kt >> 1, sub = kt & 1;
    int W = mt * 8 + sub * 4;
    uint a0 = w[W], a1 = w[W + 1], a2 = w[W + 2], a3 = w[W + 3];
    pl32swap(a0, a2);
    pl32swap(a1, a3);
    Bn[kt] = mk8(a0, a1, a2, a3);
  }
}

// perception for one scattered pixel (rt=row-in-tile, c=col-in-tile) from f32 tile
__device__ __forceinline__ void perception_px(const float* __restrict__ xt,
                                              int rt, int c, int hi, f16x8 B1h[4]) {
  uint yw[16];
#pragma unroll
  for (int kt = 0; kt < 4; ++kt) {
#pragma unroll
    for (int cp = 0; cp < 2; ++cp) {
      int ch = kt * 4 + hi * 2 + cp;
      const float* xr = &xt[(ch * 10 + rt) * 66 + c];
      float v00 = xr[0],   v01 = xr[1],   v02 = xr[2];
      float v10 = xr[66],  v11 = xr[67],  v12 = xr[68];
      float v20 = xr[132], v21 = xr[133], v22 = xr[134];
      float rs0 = v00 + v01 + v02, rs2 = v20 + v21 + v22;
      float fsx = (v02 - v00) + (v22 - v20) + 2.f * (v12 - v10);
      float fsy = (rs2 - rs0) + (v21 - v01);
      float flap = (rs0 + rs2 + v10 + v12) - 8.f * v11;
      h2v t0 = __builtin_amdgcn_cvt_pkrtz(v11, fsx);
      h2v t1 = __builtin_amdgcn_cvt_pkrtz(fsy, flap);
      yw[kt * 4 + cp * 2 + 0] = __builtin_bit_cast(uint, t0);
      yw[kt * 4 + cp * 2 + 1] = __builtin_bit_cast(uint, t1);
    }
  }
#pragma unroll
  for (int kt = 0; kt < 4; ++kt)
    B1h[kt] = mk8(yw[kt * 4], yw[kt * 4 + 1], yw[kt * 4 + 2], yw[kt * 4 + 3]);
}

// DMA one tile's interior: wave wv (0..15) covers channel wv, 10 rows (R13-identical)
__device__ __forceinline__ void issue_tile_dma(const float* __restrict__ xb,
                                               float* __restrict__ xt,
                                               int cx, int ry, int ch, int lane) {
  const int gc0 = cx * 64;
#pragma unroll
  for (int rr = 0; rr < 10; ++rr) {
    int gr = ry * 8 + rr - 1;
    float* ldst = xt + (ch * 10 + rr) * 66 + 1;
    if ((unsigned)gr < (unsigned)NH) {
      const float* g = xb + ((size_t)ch << 16) + (gr << 8) + gc0 + lane;
      gload_lds4(g, ldst);
    } else {
      ldst[lane] = 0.f;
    }
  }
}

__device__ __forceinline__ float fixup_load(const float* __restrict__ xb,
                                            int cx, int ry, int tid) {
  if (tid >= 320) return 0.f;
  int row = tid >> 1, side = tid & 1;
  int ch = row / 10;
  int rr = row - ch * 10;
  int gr = ry * 8 + rr - 1;
  int gc = cx * 64 - 1 + side * 65;
  float v = 0.f;
  if ((unsigned)gr < (unsigned)NH && (unsigned)gc < (unsigned)NW)
    v = xb[((size_t)ch << 16) + (gr << 8) + gc];
  return v;
}

__device__ __forceinline__ void fixup_store(float* __restrict__ xt, int tid, float v) {
  if (tid < 320) {
    int row = tid >> 1, side = tid & 1;
    xt[row * 66 + side * 65] = v;
  }
}

// wave0-only: compact one tile's mask into (list, flags, nact); list padded to x32
__device__ __forceinline__ void compact_tile(const float* __restrict__ mb, int tile,
                                             ushort* __restrict__ list,
                                             unsigned char* __restrict__ flags,
                                             int* __restrict__ nact_out, int lane) {
  const int cx = tile & 3, ry = (tile >> 2) & 31;
  int base = 0;
#pragma unroll
  for (int k = 0; k < 8; ++k) {
    int pp = k * 64 + lane;
    float mv = mb[((ry * 8 + k) << 8) + cx * 64 + lane];
    bool a = mv > 0.f;
    flags[pp] = a ? 1 : 0;
    ull bal = __ballot(a);
    int rank = __popcll(bal & ((1ull << lane) - 1));
    if (a) list[base + rank] = (ushort)pp;
    base += __popcll(bal);
  }
  if (base > 0) {
    int npad = (base + 31) & ~31;
    ushort lastp = list[base - 1];
    for (int i = base + lane; i < npad; i += 64) list[i] = lastp;
  }
  if (lane == 0) *nact_out = base;
}

__global__ __launch_bounds__(1024, 1)
void nca_mlp_k(const float* __restrict__ x, const float* __restrict__ wsf,
               const float* __restrict__ mask, float* __restrict__ xn) {
  extern __shared__ unsigned char smem[];
  float* xt = (float*)(smem + XT_OFF);
  ushort* lists = (ushort*)(smem + LISTS_OFF);
  unsigned char* flagbuf = smem + FLAGS_OFF;
  int* nacts = (int*)(smem + NACT_OFF);

  const int tid = threadIdx.x;
  const int lane = tid & 63;
  const int wv = tid >> 6;      // 0..15
  const int hi = lane >> 5;

  const int tile0 = blockIdx.x * 16;
  const int b = tile0 >> 7;                 // constant per block
  const float* xb = x + (size_t)b * CHW;
  float* xnb = xn + (size_t)b * CHW;
  const float* mb = mask + (size_t)b * HW;

  // ---- stage weights+bias once ----
  {
    const uint4* src = (const uint4*)wsf;
    uint4* dst = (uint4*)smem;
    for (int i = tid; i < WS_BYTES / 16; i += 1024) dst[i] = src[i];
  }
  // ---- prologue: compact tile0, DMA tile0 ----
  if (wv == 0) compact_tile(mb, tile0, lists, flagbuf, &nacts[0], lane);
  {
    int cx = tile0 & 3, ry = (tile0 >> 2) & 31;
    issue_tile_dma(xb, xt, cx, ry, wv, lane);
    float fv = fixup_load(xb, cx, ry, tid);
    fixup_store(xt, tid, fv);
  }
  __syncthreads();

  for (int t = 0; t < 16; ++t) {
    const int tile = tile0 + t;
    const int cx = tile & 3, ry = (tile >> 2) & 31;
    const int lbuf = t & 1;
    const ushort* list = lists + lbuf * 544;
    const unsigned char* flags = flagbuf + lbuf * 512;
    const int nact = nacts[lbuf];

    // ---- phase 1 (reads xt): perception for busy waves + inactive copy ----
    const bool busy = wv * 32 < nact;
    int p = 0;
    f16x8 B1[4];
    if (busy) {
      p = list[wv * 32 + (lane & 31)];
      perception_px(xt, p >> 6, p & 63, hi, B1);
    }
    {
      int pp = tid & 511;
      int gch = tid >> 9;
      int rt2 = pp >> 6, c2 = pp & 63;
      if (!flags[pp]) {
        float* xo = xnb + ((size_t)(ry * 8 + rt2) << 8) + cx * 64 + c2;
#pragma unroll
        for (int j = 0; j < 8; ++j) {
          int ch = gch * 8 + j;
          xo[(size_t)ch << 16] = xt[(ch * 10 + rt2 + 1) * 66 + c2 + 1];
        }
      }
    }
    __syncthreads();            // all xt + list reads done

    // ---- issue next tile's DMA; wave0 compacts t+1 into the other buffer ----
    float fv = 0.f;
    if (t < 15) {
      int tile2 = tile + 1;
      int cx2 = tile2 & 3, ry2 = (tile2 >> 2) & 31;
      issue_tile_dma(xb, xt, cx2, ry2, wv, lane);
      fv = fixup_load(xb, cx2, ry2, tid);
      if (wv == 0)
        compact_tile(mb, tile2, lists + (lbuf ^ 1) * 544, flagbuf + (lbuf ^ 1) * 512,
                     &nacts[lbuf ^ 1], lane);
    }

    // ---- MLP chain for busy waves only ----
    if (busy) {
      f32x16 acc[4];
      f16x8 B2[8], B3[8], B4[8];

      gemm_half<4>(smem, 0, 0, lane, hi, B1, acc);
      epilogue_swap(acc, B2);
      gemm_half<8>(smem, 1024, 128, lane, hi, B2, acc);
      epilogue_swap(acc, B3);
      gemm_half<8>(smem, 3072, 256, lane, hi, B3, acc);
      epilogue_swap(acc, B4);

      f32x16 a4;
#pragma unroll
      for (int r = 0; r < 16; ++r) a4[r] = 0.f;
      {
        const f16x8* A4 = (const f16x8*)smem + 5120 + lane;
        __builtin_amdgcn_s_setprio(1);
#pragma unroll
        for (int kt = 0; kt < 8; ++kt)
          a4 = __builtin_amdgcn_mfma_f32_32x32x16_f16(A4[kt * 64], B4[kt], a4, 0, 0, 0);
        __builtin_amdgcn_s_setprio(0);
      }

      // ---- update active px: x_new = x + dy (mask==1 on list) ----
      {
        int prow = ry * 8 + (p >> 6), pcol = cx * 64 + (p & 63);
        const float* xrb = xb + ((size_t)prow << 8) + pcol;
        float* xob = xnb + ((size_t)prow << 8) + pcol;
#pragma unroll
        for (int r = 0; r < 8; ++r) {
          int ch = (r & 3) + 8 * (r >> 2) + 4 * hi;
          xob[(size_t)ch << 16] = xrb[(size_t)ch << 16] + a4[r];
        }
      }
    }

    if (t < 15) fixup_store(xt, tid, fv);
    __syncthreads();            // DMA drained -> xt(t+1), list(t+1) ready
  }
}

// alive factor: row-block with LDS horizontal-max sharing; zero dead pixels
__global__ void alive_scale_k(const float* __restrict__ x, float* __restrict__ xn) {
  __shared__ float pm[4][258];
  const int col = threadIdx.x;
  const int row = blockIdx.x;
  const int b = blockIdx.y;
  const float NEG = -3.0e38f;
  float v0 = NEG, v1 = NEG, v2 = NEG, v3 = NEG;
  const size_t base0 = (size_t)b * CHW + ((size_t)row << 8) + col;
#pragma unroll
  for (int dr = -1; dr <= 1; ++dr) {
    int rr = row + dr;
    if ((unsigned)rr < NH) {
      long o = (long)base0 + dr * NW;
      v0 = fmaxf(v0, x[o]);
      v1 = fmaxf(v1, x[o + HW]);
      v2 = fmaxf(v2, xn[o]);
      v3 = fmaxf(v3, xn[o + HW]);
    }
  }
  pm[0][col + 1] = v0;
  pm[1][col + 1] = v1;
  pm[2][col + 1] = v2;
  pm[3][col + 1] = v3;
  if (col == 0) {
#pragma unroll
    for (int f = 0; f < 4; ++f) { pm[f][0] = NEG; pm[f][257] = NEG; }
  }
  __syncthreads();
  float p0 = fmaxf(fmaxf(pm[0][col], pm[0][col + 1]), pm[0][col + 2]);
  float p1 = fmaxf(fmaxf(pm[1][col], pm[1][col + 1]), pm[1][col + 2]);
  float p2 = fmaxf(fmaxf(pm[2][col], pm[2][col + 1]), pm[2][col + 2]);
  float p3 = fmaxf(fmaxf(pm[3][col], pm[3][col + 1]), pm[3][col + 2]);
  bool alive = ((fabsf(p0) + fabsf(p1)) > 0.01f) && ((fabsf(p2) + fabsf(p3)) > 0.01f);
  if (!alive) {
#pragma unroll
    for (int ch = 0; ch < NCH; ++ch) xn[base0 + ((size_t)ch << 16)] = 0.f;
  }
}

extern "C" void kernel_launch(void* const* d_in, const int* in_sizes, int n_in,
                              void* d_out, int out_size, void* d_ws, size_t ws_size,
                              hipStream_t stream) {
  const float* x    = (const float*)d_in[0];
  const float* w1   = (const float*)d_in[1];
  const float* b1   = (const float*)d_in[2];
  const float* w2   = (const float*)d_in[3];
  const float* b2   = (const float*)d_in[4];
  const float* w3   = (const float*)d_in[5];
  const float* b3   = (const float*)d_in[6];
  const float* w4   = (const float*)d_in[7];
  const float* mask = (const float*)d_in[8];

  float* wsf = (float*)d_ws;
  float* xn = (float*)d_out;

  hipFuncSetAttribute(reinterpret_cast<const void*>(nca_mlp_k),
                      hipFuncAttributeMaxDynamicSharedMemorySize, LDS_TOTAL);

  prep_k<<<178, 256, 0, stream>>>(w1, w2, w3, w4, b1, b2, b3, wsf);
  nca_mlp_k<<<256, 1024, LDS_TOTAL, stream>>>(x, wsf, mask, xn);
  alive_scale_k<<<dim3(NH, NB), 256, 0, stream>>>(x, xn);
}

// Round 18
// 224.235 us; speedup vs baseline: 1.4407x; 1.3955x over previous
//
#include <hip/hip_runtime.h>

typedef _Float16 f16;
typedef f16 f16x2 __attribute__((ext_vector_type(2)));
typedef f16 f16x8 __attribute__((ext_vector_type(8)));
typedef __fp16 h2v __attribute__((ext_vector_type(2)));
typedef float f32x4 __attribute__((ext_vector_type(4)));
typedef float f32x16 __attribute__((ext_vector_type(16)));
typedef unsigned int uint;
typedef unsigned short ushort;
typedef unsigned long long ull;

#define NCH 16
#define NB 32
#define NH 256
#define NW 256
#define HW 65536
#define CHW 1048576

// weight image (f16 A-frags + f32 bias frags): f16x8 idx WF1=0, WF2=1024, WF3=3072, WF4=5120
#define BIAS_BYTE 90112
#define WS_BYTES 91648
// per-wave active lists: 12 waves x 256 ushort
#define LIST_OFF WS_BYTES
#define CTR_OFF (WS_BYTES + 12*256*2)    // 97792
#define LDS_TOTAL (CTR_OFF + 16)         // 97808

__global__ void prep_k(const float* __restrict__ w1, const float* __restrict__ w2,
                       const float* __restrict__ w3, const float* __restrict__ w4,
                       const float* __restrict__ b1, const float* __restrict__ b2,
                       const float* __restrict__ b3, float* __restrict__ wsf) {
  f16* wf = (f16*)wsf;
  int id = blockIdx.x * 256 + threadIdx.x;
  if (id < 8192) {
    int j = id & 7, l = (id >> 3) & 63, mt = (id >> 9) & 3, kt = id >> 11;
    int o = mt * 32 + (l & 31), c = kt * 16 + (l >> 5) * 8 + j;
    wf[id] = (f16)w1[o * 64 + c];
  } else if (id < 24576) {
    int t = id - 8192;
    int j = t & 7, l = (t >> 3) & 63, mt = (t >> 9) & 3, kt = t >> 11;
    int o = mt * 32 + (l & 31), c = kt * 16 + (l >> 5) * 8 + j;
    wf[8192 + t] = (f16)w2[o * 128 + c];
  } else if (id < 40960) {
    int t = id - 24576;
    int j = t & 7, l = (t >> 3) & 63, mt = (t >> 9) & 3, kt = t >> 11;
    int o = mt * 32 + (l & 31), c = kt * 16 + (l >> 5) * 8 + j;
    wf[24576 + t] = (f16)w3[o * 128 + c];
  } else if (id < 45056) {
    int t = id - 40960;
    int j = t & 7, l = (t >> 3) & 63, kt = t >> 9;
    int m = l & 31, hh = l >> 5;
    int c = kt * 16 + hh * 8 + j;
    wf[40960 + t] = (m < 16) ? (f16)w4[m * 128 + c] : (f16)0.f;
  } else if (id < 45440) {
    int t = id - 45056;
    int r = t & 15, hh = (t >> 4) & 1, mt = (t >> 5) & 3, ly = t >> 7;
    const float* bb = (ly == 0) ? b1 : (ly == 1) ? b2 : b3;
    ((float*)((unsigned char*)wsf + BIAS_BYTE))[t] =
        bb[mt * 32 + (r & 3) + 8 * (r >> 2) + 4 * hh];
  }
}

// dense base copy: xn = x (active px overwritten later by nca_sparse_k)
__global__ __launch_bounds__(256)
void copy_k(const float4* __restrict__ x4, float4* __restrict__ xn4) {
  const size_t total = (size_t)NB * CHW / 4;
  for (size_t i = (size_t)blockIdx.x * 256 + threadIdx.x; i < total; i += (size_t)2048 * 256)
    xn4[i] = x4[i];
}

__device__ __forceinline__ void pl32swap(uint& a, uint& b) {
  asm volatile("v_permlane32_swap_b32 %0, %1" : "+v"(a), "+v"(b));
}

__device__ __forceinline__ f16x8 mk8(uint a, uint b, uint c, uint d) {
  union { uint u[4]; f16x8 v; } z;
  z.u[0] = a; z.u[1] = b; z.u[2] = c; z.u[3] = d;
  return z.v;
}

// Single-half layer: bias init from LDS frags + MFMA cluster (R13-identical)
template <int NKT>
__device__ __forceinline__ void gemm_half(const unsigned char* __restrict__ smem,
                                          int wfFragBase, int biasFloatOff, int lane, int hi,
                                          const f16x8* __restrict__ B, f32x16 acc[4]) {
#pragma unroll
  for (int mt = 0; mt < 4; ++mt) {
    const f32x16* bp =
        (const f32x16*)(smem + BIAS_BYTE + 4 * (biasFloatOff + (mt * 2 + hi) * 16));
    acc[mt] = *bp;
  }
  const f16x8* A = (const f16x8*)smem + wfFragBase + lane;
  __builtin_amdgcn_s_setprio(1);
#pragma unroll
  for (int kt = 0; kt < NKT; ++kt) {
#pragma unroll
    for (int mt = 0; mt < 4; ++mt) {
      f16x8 a = A[(kt * 4 + mt) * 64];
      acc[mt] = __builtin_amdgcn_mfma_f32_32x32x16_f16(a, B[kt], acc[mt], 0, 0, 0);
    }
  }
  __builtin_amdgcn_s_setprio(0);
}

// lrelu in packed f16 -> permlane -> next B-frags (R13-identical)
__device__ __forceinline__ void epilogue_swap(const f32x16 acc[4], f16x8 Bn[8]) {
  uint w[32];
  const h2v c001 = {(__fp16)0.01f, (__fp16)0.01f};
#pragma unroll
  for (int mt = 0; mt < 4; ++mt) {
#pragma unroll
    for (int i = 0; i < 8; ++i) {
      h2v u = __builtin_amdgcn_cvt_pkrtz(acc[mt][2 * i], acc[mt][2 * i + 1]);
      h2v s = u * c001;
      h2v m = __builtin_elementwise_max(u, s);
      w[mt * 8 + i] = __builtin_bit_cast(uint, m);
    }
  }
#pragma unroll
  for (int kt = 0; kt < 8; ++kt) {
    int mt = kt >> 1, sub = kt & 1;
    int W = mt * 8 + sub * 4;
    uint a0 = w[W], a1 = w[W + 1], a2 = w[W + 2], a3 = w[W + 3];
    pl32swap(a0, a2);
    pl32swap(a1, a3);
    Bn[kt] = mk8(a0, a1, a2, a3);
  }
}

// perception for one pixel straight from global x; zero-padded borders per-lane
__device__ __forceinline__ void perc_gpx(const float* __restrict__ xb, int row, int col,
                                         int hi, f16x8 B1h[4]) {
  const bool fU = row > 0, fD = row < NH - 1, fL = col > 0, fR = col < NW - 1;
  const int rU = fU ? row - 1 : row, rD = fD ? row + 1 : row;
  const int cL = fL ? col - 1 : col, cR = fR ? col + 1 : col;
  uint yw[16];
#pragma unroll
  for (int kt = 0; kt < 4; ++kt) {
#pragma unroll
    for (int cp = 0; cp < 2; ++cp) {
      const int c = kt * 4 + hi * 2 + cp;
      const float* base = xb + ((size_t)c << 16);
      const float* pm = base + (row << 8);
      const float* pu = base + (rU << 8);
      const float* pd = base + (rD << 8);
      float v11 = pm[col];
      float v10 = fL ? pm[cL] : 0.f;
      float v12 = fR ? pm[cR] : 0.f;
      float v01 = fU ? pu[col] : 0.f;
      float v00 = (fU && fL) ? pu[cL] : 0.f;
      float v02 = (fU && fR) ? pu[cR] : 0.f;
      float v21 = fD ? pd[col] : 0.f;
      float v20 = (fD && fL) ? pd[cL] : 0.f;
      float v22 = (fD && fR) ? pd[cR] : 0.f;
      float rs0 = v00 + v01 + v02, rs2 = v20 + v21 + v22;
      float fsx = (v02 - v00) + (v22 - v20) + 2.f * (v12 - v10);
      float fsy = (rs2 - rs0) + (v21 - v01);
      float flap = (rs0 + rs2 + v10 + v12) - 8.f * v11;
      h2v t0 = __builtin_amdgcn_cvt_pkrtz(v11, fsx);
      h2v t1 = __builtin_amdgcn_cvt_pkrtz(fsy, flap);
      yw[kt * 4 + cp * 2 + 0] = __builtin_bit_cast(uint, t0);
      yw[kt * 4 + cp * 2 + 1] = __builtin_bit_cast(uint, t1);
    }
  }
#pragma unroll
  for (int kt = 0; kt < 4; ++kt)
    B1h[kt] = mk8(yw[kt * 4], yw[kt * 4 + 1], yw[kt * 4 + 2], yw[kt * 4 + 3]);
}

// Sparse MLP: block = (image b, 32-row slice); waves claim 1-row strips dynamically,
// compact actives, run the MLP only on active pixels. No barriers in the work loop.
__global__ __launch_bounds__(768, 1)
void nca_sparse_k(const float* __restrict__ x, const float* __restrict__ wsf,
                  const float* __restrict__ mask, float* __restrict__ xn) {
  extern __shared__ unsigned char smem[];
  ushort* lists = (ushort*)(smem + LIST_OFF);
  int* ctr = (int*)(smem + CTR_OFF);

  const int tid = threadIdx.x;
  const int lane = tid & 63;
  const int wv = tid >> 6;        // 0..11
  const int hi = lane >> 5;

  const int b = blockIdx.x >> 3;
  const int row0 = (blockIdx.x & 7) * 32;
  const float* xb = x + (size_t)b * CHW;
  float* xnb = xn + (size_t)b * CHW;
  const float* mb = mask + (size_t)b * HW;

  // ---- stage weights+bias once ----
  {
    const uint4* src = (const uint4*)wsf;
    uint4* dst = (uint4*)smem;
    for (int i = tid; i < WS_BYTES / 16; i += 768) dst[i] = src[i];
  }
  if (tid == 0) *ctr = 0;
  __syncthreads();                // the only block barrier

  ushort* mylist = lists + wv * 256;

  for (;;) {
    int s;
    if (lane == 0) s = atomicAdd(ctr, 1);
    s = __shfl(s, 0);
    if (s >= 32) break;
    const int row = row0 + s;

    // ---- compact strip (1 row, 256 px), ordered ----
    int c = 0;
#pragma unroll
    for (int k2 = 0; k2 < 4; ++k2) {
      int cc = k2 * 64 + lane;
      bool a = mb[(row << 8) + cc] > 0.f;
      ull bal = __ballot(a);
      int rank = __popcll(bal & ((1ull << lane) - 1));
      if (a) mylist[c + rank] = (ushort)cc;
      c += __popcll(bal);
    }
    const int nb = (c + 31) >> 5;

    for (int k = 0; k < nb; ++k) {
      int idx = k * 32 + (lane & 31);
      if (idx >= c) idx = c - 1;          // dup last px: benign same-value race
      const int col = mylist[idx];

      f16x8 B1[4];
      perc_gpx(xb, row, col, hi, B1);

      f32x16 acc[4];
      f16x8 B2[8], B3[8], B4[8];
      gemm_half<4>(smem, 0, 0, lane, hi, B1, acc);
      epilogue_swap(acc, B2);
      gemm_half<8>(smem, 1024, 128, lane, hi, B2, acc);
      epilogue_swap(acc, B3);
      gemm_half<8>(smem, 3072, 256, lane, hi, B3, acc);
      epilogue_swap(acc, B4);

      f32x16 a4;
#pragma unroll
      for (int r = 0; r < 16; ++r) a4[r] = 0.f;
      {
        const f16x8* A4 = (const f16x8*)smem + 5120 + lane;
        __builtin_amdgcn_s_setprio(1);
#pragma unroll
        for (int kt = 0; kt < 8; ++kt)
          a4 = __builtin_amdgcn_mfma_f32_32x32x16_f16(A4[kt * 64], B4[kt], a4, 0, 0, 0);
        __builtin_amdgcn_s_setprio(0);
      }

      // ---- update active px: mask==1 -> x + dy ----
      {
        const float* xrb = xb + (row << 8) + col;
        float* xob = xnb + (row << 8) + col;
#pragma unroll
        for (int r = 0; r < 8; ++r) {
          int ch = (r & 3) + 8 * (r >> 2) + 4 * hi;
          xob[(size_t)ch << 16] = xrb[(size_t)ch << 16] + a4[r];
        }
      }
    }
  }
}

// alive factor: row-block with LDS horizontal-max sharing; zero dead pixels
__global__ void alive_scale_k(const float* __restrict__ x, float* __restrict__ xn) {
  __shared__ float pm[4][258];
  const int col = threadIdx.x;
  const int row = blockIdx.x;
  const int b = blockIdx.y;
  const float NEG = -3.0e38f;
  float v0 = NEG, v1 = NEG, v2 = NEG, v3 = NEG;
  const size_t base0 = (size_t)b * CHW + ((size_t)row << 8) + col;
#pragma unroll
  for (int dr = -1; dr <= 1; ++dr) {
    int rr = row + dr;
    if ((unsigned)rr < NH) {
      long o = (long)base0 + dr * NW;
      v0 = fmaxf(v0, x[o]);
      v1 = fmaxf(v1, x[o + HW]);
      v2 = fmaxf(v2, xn[o]);
      v3 = fmaxf(v3, xn[o + HW]);
    }
  }
  pm[0][col + 1] = v0;
  pm[1][col + 1] = v1;
  pm[2][col + 1] = v2;
  pm[3][col + 1] = v3;
  if (col == 0) {
#pragma unroll
    for (int f = 0; f < 4; ++f) { pm[f][0] = NEG; pm[f][257] = NEG; }
  }
  __syncthreads();
  float p0 = fmaxf(fmaxf(pm[0][col], pm[0][col + 1]), pm[0][col + 2]);
  float p1 = fmaxf(fmaxf(pm[1][col], pm[1][col + 1]), pm[1][col + 2]);
  float p2 = fmaxf(fmaxf(pm[2][col], pm[2][col + 1]), pm[2][col + 2]);
  float p3 = fmaxf(fmaxf(pm[3][col], pm[3][col + 1]), pm[3][col + 2]);
  bool alive = ((fabsf(p0) + fabsf(p1)) > 0.01f) && ((fabsf(p2) + fabsf(p3)) > 0.01f);
  if (!alive) {
#pragma unroll
    for (int ch = 0; ch < NCH; ++ch) xn[base0 + ((size_t)ch << 16)] = 0.f;
  }
}

extern "C" void kernel_launch(void* const* d_in, const int* in_sizes, int n_in,
                              void* d_out, int out_size, void* d_ws, size_t ws_size,
                              hipStream_t stream) {
  const float* x    = (const float*)d_in[0];
  const float* w1   = (const float*)d_in[1];
  const float* b1   = (const float*)d_in[2];
  const float* w2   = (const float*)d_in[3];
  const float* b2   = (const float*)d_in[4];
  const float* w3   = (const float*)d_in[5];
  const float* b3   = (const float*)d_in[6];
  const float* w4   = (const float*)d_in[7];
  const float* mask = (const float*)d_in[8];

  float* wsf = (float*)d_ws;
  float* xn = (float*)d_out;

  hipFuncSetAttribute(reinterpret_cast<const void*>(nca_sparse_k),
                      hipFuncAttributeMaxDynamicSharedMemorySize, LDS_TOTAL);

  prep_k<<<178, 256, 0, stream>>>(w1, w2, w3, w4, b1, b2, b3, wsf);
  copy_k<<<2048, 256, 0, stream>>>((const float4*)x, (float4*)xn);
  nca_sparse_k<<<256, 768, LDS_TOTAL, stream>>>(x, wsf, mask, xn);
  alive_scale_k<<<dim3(NH, NB), 256, 0, stream>>>(x, xn);
}

// Round 19
// 218.428 us; speedup vs baseline: 1.4790x; 1.0266x over previous
//
#include <hip/hip_runtime.h>

typedef _Float16 f16;
typedef f16 f16x2 __attribute__((ext_vector_type(2)));
typedef f16 f16x8 __attribute__((ext_vector_type(8)));
typedef __fp16 h2v __attribute__((ext_vector_type(2)));
typedef float f32x4 __attribute__((ext_vector_type(4)));
typedef float f32x16 __attribute__((ext_vector_type(16)));
typedef unsigned int uint;
typedef unsigned short ushort;
typedef unsigned long long ull;

#define NCH 16
#define NB 32
#define NH 256
#define NW 256
#define HW 65536
#define CHW 1048576

// weight image (f16 A-frags + f32 bias frags): f16x8 idx WF1=0, WF2=1024, WF3=3072, WF4=5120
#define BIAS_BYTE 90112
#define WS_BYTES 91648
// band: f16 [stage_row7][col256][16ch packed, half-swizzled] = 32B/px
#define BAND_ROWS 5
#define STAGE_ROWS 7
#define XBAND_OFF WS_BYTES                   // 91648
#define XBAND_BYTES (STAGE_ROWS*256*32)      // 57344
#define LIST_OFF (XBAND_OFF + XBAND_BYTES)   // 148992
#define LIST_MAX (BAND_ROWS*256)             // 1280
#define CTR_OFF (LIST_OFF + LIST_MAX*2)      // 151552
#define LDS_TOTAL (CTR_OFF + 16)             // 151568
#define NBANDS_PER_IMG 52                    // ceil(256/5)
#define NBANDS_TOTAL (NB*NBANDS_PER_IMG)     // 1664

__global__ void prep_k(const float* __restrict__ w1, const float* __restrict__ w2,
                       const float* __restrict__ w3, const float* __restrict__ w4,
                       const float* __restrict__ b1, const float* __restrict__ b2,
                       const float* __restrict__ b3, float* __restrict__ wsf) {
  f16* wf = (f16*)wsf;
  int id = blockIdx.x * 256 + threadIdx.x;
  if (id < 8192) {
    int j = id & 7, l = (id >> 3) & 63, mt = (id >> 9) & 3, kt = id >> 11;
    int o = mt * 32 + (l & 31), c = kt * 16 + (l >> 5) * 8 + j;
    wf[id] = (f16)w1[o * 64 + c];
  } else if (id < 24576) {
    int t = id - 8192;
    int j = t & 7, l = (t >> 3) & 63, mt = (t >> 9) & 3, kt = t >> 11;
    int o = mt * 32 + (l & 31), c = kt * 16 + (l >> 5) * 8 + j;
    wf[8192 + t] = (f16)w2[o * 128 + c];
  } else if (id < 40960) {
    int t = id - 24576;
    int j = t & 7, l = (t >> 3) & 63, mt = (t >> 9) & 3, kt = t >> 11;
    int o = mt * 32 + (l & 31), c = kt * 16 + (l >> 5) * 8 + j;
    wf[24576 + t] = (f16)w3[o * 128 + c];
  } else if (id < 45056) {
    int t = id - 40960;
    int j = t & 7, l = (t >> 3) & 63, kt = t >> 9;
    int m = l & 31, hh = l >> 5;
    int c = kt * 16 + hh * 8 + j;
    wf[40960 + t] = (m < 16) ? (f16)w4[m * 128 + c] : (f16)0.f;
  } else if (id < 45440) {
    int t = id - 45056;
    int r = t & 15, hh = (t >> 4) & 1, mt = (t >> 5) & 3, ly = t >> 7;
    const float* bb = (ly == 0) ? b1 : (ly == 1) ? b2 : b3;
    ((float*)((unsigned char*)wsf + BIAS_BYTE))[t] =
        bb[mt * 32 + (r & 3) + 8 * (r >> 2) + 4 * hh];
  }
}

// dense base copy: xn = x (active px overwritten later by nca_band_k)
__global__ __launch_bounds__(256)
void copy_k(const float4* __restrict__ x4, float4* __restrict__ xn4) {
  const size_t total = (size_t)NB * CHW / 4;
  for (size_t i = (size_t)blockIdx.x * 256 + threadIdx.x; i < total; i += (size_t)2048 * 256)
    xn4[i] = x4[i];
}

__device__ __forceinline__ void pl32swap(uint& a, uint& b) {
  asm volatile("v_permlane32_swap_b32 %0, %1" : "+v"(a), "+v"(b));
}

__device__ __forceinline__ f16x8 mk8(uint a, uint b, uint c, uint d) {
  union { uint u[4]; f16x8 v; } z;
  z.u[0] = a; z.u[1] = b; z.u[2] = c; z.u[3] = d;
  return z.v;
}

// Single-half layer: bias init from LDS frags + MFMA cluster (R13/R18-identical)
template <int NKT>
__device__ __forceinline__ void gemm_half(const unsigned char* __restrict__ smem,
                                          int wfFragBase, int biasFloatOff, int lane, int hi,
                                          const f16x8* __restrict__ B, f32x16 acc[4]) {
#pragma unroll
  for (int mt = 0; mt < 4; ++mt) {
    const f32x16* bp =
        (const f32x16*)(smem + BIAS_BYTE + 4 * (biasFloatOff + (mt * 2 + hi) * 16));
    acc[mt] = *bp;
  }
  const f16x8* A = (const f16x8*)smem + wfFragBase + lane;
  __builtin_amdgcn_s_setprio(1);
#pragma unroll
  for (int kt = 0; kt < NKT; ++kt) {
#pragma unroll
    for (int mt = 0; mt < 4; ++mt) {
      f16x8 a = A[(kt * 4 + mt) * 64];
      acc[mt] = __builtin_amdgcn_mfma_f32_32x32x16_f16(a, B[kt], acc[mt], 0, 0, 0);
    }
  }
  __builtin_amdgcn_s_setprio(0);
}

// lrelu in packed f16 -> permlane -> next B-frags (R13/R18-identical)
__device__ __forceinline__ void epilogue_swap(const f32x16 acc[4], f16x8 Bn[8]) {
  uint w[32];
  const h2v c001 = {(__fp16)0.01f, (__fp16)0.01f};
#pragma unroll
  for (int mt = 0; mt < 4; ++mt) {
#pragma unroll
    for (int i = 0; i < 8; ++i) {
      h2v u = __builtin_amdgcn_cvt_pkrtz(acc[mt][2 * i], acc[mt][2 * i + 1]);
      h2v s = u * c001;
      h2v m = __builtin_elementwise_max(u, s);
      w[mt * 8 + i] = __builtin_bit_cast(uint, m);
    }
  }
#pragma unroll
  for (int kt = 0; kt < 8; ++kt) {
    int mt = kt >> 1, sub = kt & 1;
    int W = mt * 8 + sub * 4;
    uint a0 = w[W], a1 = w[W + 1], a2 = w[W + 2], a3 = w[W + 3];
    pl32swap(a0, a2);
    pl32swap(a1, a3);
    Bn[kt] = mk8(a0, a1, a2, a3);
  }
}

// perception for one active pixel from the f16 band in LDS: 9 ds_read_b128
// band slot order (R8-validated): half=(ch>>1)&1 (==hi of consumer), j=(ch>>2)*2+(ch&1)
// byte addr = (sr*256+col)*32 + ((half ^ (col&1))<<4) + j*2
__device__ __forceinline__ void perc_band(const unsigned char* __restrict__ xband,
                                          int rl, int c, int hi, f16x8 B1h[4]) {
  const bool fL = c > 0, fR = c < NW - 1;
  const int cm = fL ? c - 1 : c, cp2 = fR ? c + 1 : c;
  const int swm = (hi ^ (cm & 1)) << 4;
  const int swc = (hi ^ (c & 1)) << 4;
  const int swp = (hi ^ (cp2 & 1)) << 4;
  union U4 { uint4 u; f16 hh[8]; };
  U4 q[9];
#pragma unroll
  for (int dr = 0; dr < 3; ++dr) {
    const unsigned char* rowp = xband + (size_t)(rl + dr) * 256 * 32;
    q[dr * 3 + 0].u = *(const uint4*)(rowp + cm * 32 + swm);
    q[dr * 3 + 1].u = *(const uint4*)(rowp + c * 32 + swc);
    q[dr * 3 + 2].u = *(const uint4*)(rowp + cp2 * 32 + swp);
  }
  uint yw[16];
#pragma unroll
  for (int j = 0; j < 8; ++j) {
    float v00 = (float)q[0].hh[j], v01 = (float)q[1].hh[j], v02 = (float)q[2].hh[j];
    float v10 = (float)q[3].hh[j], v11 = (float)q[4].hh[j], v12 = (float)q[5].hh[j];
    float v20 = (float)q[6].hh[j], v21 = (float)q[7].hh[j], v22 = (float)q[8].hh[j];
    if (!fL) { v00 = 0.f; v10 = 0.f; v20 = 0.f; }
    if (!fR) { v02 = 0.f; v12 = 0.f; v22 = 0.f; }
    float rs0 = v00 + v01 + v02, rs2 = v20 + v21 + v22;
    float fsx = (v02 - v00) + (v22 - v20) + 2.f * (v12 - v10);
    float fsy = (rs2 - rs0) + (v21 - v01);
    float flap = (rs0 + rs2 + v10 + v12) - 8.f * v11;
    h2v t0 = __builtin_amdgcn_cvt_pkrtz(v11, fsx);
    h2v t1 = __builtin_amdgcn_cvt_pkrtz(fsy, flap);
    int kt = j >> 1, cp = j & 1;
    yw[kt * 4 + cp * 2 + 0] = __builtin_bit_cast(uint, t0);
    yw[kt * 4 + cp * 2 + 1] = __builtin_bit_cast(uint, t1);
  }
#pragma unroll
  for (int kt = 0; kt < 4; ++kt)
    B1h[kt] = mk8(yw[kt * 4], yw[kt * 4 + 1], yw[kt * 4 + 2], yw[kt * 4 + 3]);
}

// Sparse band kernel: persistent 256 blocks x 768 thr; per band: stage f16 band
// (coalesced) + compact actives -> barrier -> MLP on active batches only.
__global__ __launch_bounds__(768, 1)
void nca_band_k(const float* __restrict__ x, const float* __restrict__ wsf,
                const float* __restrict__ mask, float* __restrict__ xn) {
  extern __shared__ unsigned char smem[];
  unsigned char* xband = smem + XBAND_OFF;
  ushort* list = (ushort*)(smem + LIST_OFF);
  int* ctr = (int*)(smem + CTR_OFF);

  const int tid = threadIdx.x;
  const int lane = tid & 63;
  const int wv = tid >> 6;        // 0..11
  const int hi = lane >> 5;

  // ---- stage weights+bias once ----
  {
    const uint4* src = (const uint4*)wsf;
    uint4* dst = (uint4*)smem;
    for (int i = tid; i < WS_BYTES / 16; i += 768) dst[i] = src[i];
  }
  __syncthreads();

  for (int band = blockIdx.x; band < NBANDS_TOTAL; band += 256) {
    const int b = band / NBANDS_PER_IMG;
    const int r0 = (band - b * NBANDS_PER_IMG) * BAND_ROWS;
    const float* xb = x + (size_t)b * CHW;
    float* xnb = xn + (size_t)b * CHW;
    const float* mb = mask + (size_t)b * HW;

    if (tid == 0) *ctr = 0;
    __syncthreads();

    // ---- stage band: rows r0-1 .. r0+5 as f16 channel-interleaved ----
    for (int e = tid; e < STAGE_ROWS * 16 * 64; e += 768) {
      int cg = e & 63;          // 4-col group
      int pair = e >> 6;        // (sr, ch)
      int sr = pair >> 4;
      int ch = pair & 15;
      int gr = r0 - 1 + sr;
      f32x4 v = {0.f, 0.f, 0.f, 0.f};
      if ((unsigned)gr < (unsigned)NH)
        v = *(const f32x4*)(xb + ((size_t)ch << 16) + (gr << 8) + cg * 4);
      int half = (ch >> 1) & 1;
      int j = (ch >> 2) * 2 + (ch & 1);
      unsigned char* base = xband + (size_t)(sr * 256 + cg * 4) * 32;
#pragma unroll
      for (int k = 0; k < 4; ++k) {
        *(f16*)(base + k * 32 + ((half ^ (k & 1)) << 4) + j * 2) = (f16)v[k];
      }
    }

    // ---- compact actives: wave w (<5) handles row r0+w ----
    if (wv < BAND_ROWS) {
      int row = r0 + wv;
      if (row < NH) {
        ull bal[4];
        int c = 0;
#pragma unroll
        for (int k = 0; k < 4; ++k) {
          bool a = mb[(row << 8) + k * 64 + lane] > 0.f;
          bal[k] = __ballot(a);
          c += __popcll(bal[k]);
        }
        int base;
        if (lane == 0) base = atomicAdd(ctr, c);
        base = __shfl(base, 0);
#pragma unroll
        for (int k = 0; k < 4; ++k) {
          int rank = __popcll(bal[k] & ((1ull << lane) - 1));
          if ((bal[k] >> lane) & 1ull)
            list[base + rank] = (ushort)((wv << 8) | (k * 64 + lane));
          base += __popcll(bal[k]);
        }
      }
    }
    __syncthreads();

    // ---- MLP on active batches ----
    const int n = *ctr;
    const int nbatch = (n + 31) >> 5;
    for (int k = wv; k < nbatch; k += 12) {
      int idx = k * 32 + (lane & 31);
      if (idx >= n) idx = n - 1;
      const int entry = list[idx];
      const int rl = entry >> 8, c = entry & 255;

      f16x8 B1[4];
      perc_band(xband, rl, c, hi, B1);

      f32x16 acc[4];
      f16x8 B2[8], B3[8], B4[8];
      gemm_half<4>(smem, 0, 0, lane, hi, B1, acc);
      epilogue_swap(acc, B2);
      gemm_half<8>(smem, 1024, 128, lane, hi, B2, acc);
      epilogue_swap(acc, B3);
      gemm_half<8>(smem, 3072, 256, lane, hi, B3, acc);
      epilogue_swap(acc, B4);

      f32x16 a4;
#pragma unroll
      for (int r = 0; r < 16; ++r) a4[r] = 0.f;
      {
        const f16x8* A4 = (const f16x8*)smem + 5120 + lane;
        __builtin_amdgcn_s_setprio(1);
#pragma unroll
        for (int kt = 0; kt < 8; ++kt)
          a4 = __builtin_amdgcn_mfma_f32_32x32x16_f16(A4[kt * 64], B4[kt], a4, 0, 0, 0);
        __builtin_amdgcn_s_setprio(0);
      }

      // update active px: mask==1 -> x + dy (exact f32 x re-read)
      {
        const int row = r0 + rl;
        const float* xrb = xb + (row << 8) + c;
        float* xob = xnb + (row << 8) + c;
#pragma unroll
        for (int r = 0; r < 8; ++r) {
          int ch = (r & 3) + 8 * (r >> 2) + 4 * hi;
          xob[(size_t)ch << 16] = xrb[(size_t)ch << 16] + a4[r];
        }
      }
    }
    __syncthreads();   // band LDS free for next iteration
  }
}

// alive factor: row-block with LDS horizontal-max sharing; zero dead pixels
__global__ void alive_scale_k(const float* __restrict__ x, float* __restrict__ xn) {
  __shared__ float pm[4][258];
  const int col = threadIdx.x;
  const int row = blockIdx.x;
  const int b = blockIdx.y;
  const float NEG = -3.0e38f;
  float v0 = NEG, v1 = NEG, v2 = NEG, v3 = NEG;
  const size_t base0 = (size_t)b * CHW + ((size_t)row << 8) + col;
#pragma unroll
  for (int dr = -1; dr <= 1; ++dr) {
    int rr = row + dr;
    if ((unsigned)rr < NH) {
      long o = (long)base0 + dr * NW;
      v0 = fmaxf(v0, x[o]);
      v1 = fmaxf(v1, x[o + HW]);
      v2 = fmaxf(v2, xn[o]);
      v3 = fmaxf(v3, xn[o + HW]);
    }
  }
  pm[0][col + 1] = v0;
  pm[1][col + 1] = v1;
  pm[2][col + 1] = v2;
  pm[3][col + 1] = v3;
  if (col == 0) {
#pragma unroll
    for (int f = 0; f < 4; ++f) { pm[f][0] = NEG; pm[f][257] = NEG; }
  }
  __syncthreads();
  float p0 = fmaxf(fmaxf(pm[0][col], pm[0][col + 1]), pm[0][col + 2]);
  float p1 = fmaxf(fmaxf(pm[1][col], pm[1][col + 1]), pm[1][col + 2]);
  float p2 = fmaxf(fmaxf(pm[2][col], pm[2][col + 1]), pm[2][col + 2]);
  float p3 = fmaxf(fmaxf(pm[3][col], pm[3][col + 1]), pm[3][col + 2]);
  bool alive = ((fabsf(p0) + fabsf(p1)) > 0.01f) && ((fabsf(p2) + fabsf(p3)) > 0.01f);
  if (!alive) {
#pragma unroll
    for (int ch = 0; ch < NCH; ++ch) xn[base0 + ((size_t)ch << 16)] = 0.f;
  }
}

extern "C" void kernel_launch(void* const* d_in, const int* in_sizes, int n_in,
                              void* d_out, int out_size, void* d_ws, size_t ws_size,
                              hipStream_t stream) {
  const float* x    = (const float*)d_in[0];
  const float* w1   = (const float*)d_in[1];
  const float* b1   = (const float*)d_in[2];
  const float* w2   = (const float*)d_in[3];
  const float* b2   = (const float*)d_in[4];
  const float* w3   = (const float*)d_in[5];
  const float* b3   = (const float*)d_in[6];
  const float* w4   = (const float*)d_in[7];
  const float* mask = (const float*)d_in[8];

  float* wsf = (float*)d_ws;
  float* xn = (float*)d_out;

  hipFuncSetAttribute(reinterpret_cast<const void*>(nca_band_k),
                      hipFuncAttributeMaxDynamicSharedMemorySize, LDS_TOTAL);

  prep_k<<<178, 256, 0, stream>>>(w1, w2, w3, w4, b1, b2, b3, wsf);
  copy_k<<<2048, 256, 0, stream>>>((const float4*)x, (float4*)xn);
  nca_band_k<<<256, 768, LDS_TOTAL, stream>>>(x, wsf, mask, xn);
  alive_scale_k<<<dim3(NH, NB), 256, 0, stream>>>(x, xn);
}

// Round 20
// 183.318 us; speedup vs baseline: 1.7623x; 1.1915x over previous
//
#include <hip/hip_runtime.h>

typedef _Float16 f16;
typedef f16 f16x2 __attribute__((ext_vector_type(2)));
typedef f16 f16x8 __attribute__((ext_vector_type(8)));
typedef __fp16 h2v __attribute__((ext_vector_type(2)));
typedef float f32x4 __attribute__((ext_vector_type(4)));
typedef float f32x16 __attribute__((ext_vector_type(16)));
typedef unsigned int uint;
typedef unsigned short ushort;
typedef unsigned long long ull;

#define NCH 16
#define NB 32
#define NH 256
#define NW 256
#define HW 65536
#define CHW 1048576

// weight image (f16 A-frags + f32 bias frags): f16x8 idx WF1=0, WF2=1024, WF3=3072, WF4=5120
#define BIAS_BYTE 90112
#define WS_BYTES 91648
// band: f16 [stage_row7][col256][16ch packed, half-swizzled] = 32B/px
#define BAND_ROWS 5
#define STAGE_ROWS 7
#define XBAND_OFF WS_BYTES                   // 91648
#define XBAND_BYTES (STAGE_ROWS*256*32)      // 57344
#define LIST_OFF (XBAND_OFF + XBAND_BYTES)   // 148992
#define LIST_MAX (BAND_ROWS*256)             // 1280
#define CTR_OFF (LIST_OFF + LIST_MAX*2)      // 151552
#define LDS_TOTAL (CTR_OFF + 16)             // 151568
#define NBANDS_PER_IMG 52                    // ceil(256/5)
#define NBANDS_TOTAL (NB*NBANDS_PER_IMG)     // 1664

__global__ void prep_k(const float* __restrict__ w1, const float* __restrict__ w2,
                       const float* __restrict__ w3, const float* __restrict__ w4,
                       const float* __restrict__ b1, const float* __restrict__ b2,
                       const float* __restrict__ b3, float* __restrict__ wsf) {
  f16* wf = (f16*)wsf;
  int id = blockIdx.x * 256 + threadIdx.x;
  if (id < 8192) {
    int j = id & 7, l = (id >> 3) & 63, mt = (id >> 9) & 3, kt = id >> 11;
    int o = mt * 32 + (l & 31), c = kt * 16 + (l >> 5) * 8 + j;
    wf[id] = (f16)w1[o * 64 + c];
  } else if (id < 24576) {
    int t = id - 8192;
    int j = t & 7, l = (t >> 3) & 63, mt = (t >> 9) & 3, kt = t >> 11;
    int o = mt * 32 + (l & 31), c = kt * 16 + (l >> 5) * 8 + j;
    wf[8192 + t] = (f16)w2[o * 128 + c];
  } else if (id < 40960) {
    int t = id - 24576;
    int j = t & 7, l = (t >> 3) & 63, mt = (t >> 9) & 3, kt = t >> 11;
    int o = mt * 32 + (l & 31), c = kt * 16 + (l >> 5) * 8 + j;
    wf[24576 + t] = (f16)w3[o * 128 + c];
  } else if (id < 45056) {
    int t = id - 40960;
    int j = t & 7, l = (t >> 3) & 63, kt = t >> 9;
    int m = l & 31, hh = l >> 5;
    int c = kt * 16 + hh * 8 + j;
    wf[40960 + t] = (m < 16) ? (f16)w4[m * 128 + c] : (f16)0.f;
  } else if (id < 45440) {
    int t = id - 45056;
    int r = t & 15, hh = (t >> 4) & 1, mt = (t >> 5) & 3, ly = t >> 7;
    const float* bb = (ly == 0) ? b1 : (ly == 1) ? b2 : b3;
    ((float*)((unsigned char*)wsf + BIAS_BYTE))[t] =
        bb[mt * 32 + (r & 3) + 8 * (r >> 2) + 4 * hh];
  }
}

// dense base copy: xn = x (active px overwritten later by nca_band_k)
__global__ __launch_bounds__(256)
void copy_k(const float4* __restrict__ x4, float4* __restrict__ xn4) {
  const size_t total = (size_t)NB * CHW / 4;
  for (size_t i = (size_t)blockIdx.x * 256 + threadIdx.x; i < total; i += (size_t)2048 * 256)
    xn4[i] = x4[i];
}

__device__ __forceinline__ void pl32swap(uint& a, uint& b) {
  asm volatile("v_permlane32_swap_b32 %0, %1" : "+v"(a), "+v"(b));
}

__device__ __forceinline__ f16x8 mk8(uint a, uint b, uint c, uint d) {
  union { uint u[4]; f16x8 v; } z;
  z.u[0] = a; z.u[1] = b; z.u[2] = c; z.u[3] = d;
  return z.v;
}

// Single-half layer: bias init from LDS frags + MFMA cluster (R13/R18-identical)
template <int NKT>
__device__ __forceinline__ void gemm_half(const unsigned char* __restrict__ smem,
                                          int wfFragBase, int biasFloatOff, int lane, int hi,
                                          const f16x8* __restrict__ B, f32x16 acc[4]) {
#pragma unroll
  for (int mt = 0; mt < 4; ++mt) {
    const f32x16* bp =
        (const f32x16*)(smem + BIAS_BYTE + 4 * (biasFloatOff + (mt * 2 + hi) * 16));
    acc[mt] = *bp;
  }
  const f16x8* A = (const f16x8*)smem + wfFragBase + lane;
  __builtin_amdgcn_s_setprio(1);
#pragma unroll
  for (int kt = 0; kt < NKT; ++kt) {
#pragma unroll
    for (int mt = 0; mt < 4; ++mt) {
      f16x8 a = A[(kt * 4 + mt) * 64];
      acc[mt] = __builtin_amdgcn_mfma_f32_32x32x16_f16(a, B[kt], acc[mt], 0, 0, 0);
    }
  }
  __builtin_amdgcn_s_setprio(0);
}

// lrelu in packed f16 -> permlane -> next B-frags (R13/R18-identical)
__device__ __forceinline__ void epilogue_swap(const f32x16 acc[4], f16x8 Bn[8]) {
  uint w[32];
  const h2v c001 = {(__fp16)0.01f, (__fp16)0.01f};
#pragma unroll
  for (int mt = 0; mt < 4; ++mt) {
#pragma unroll
    for (int i = 0; i < 8; ++i) {
      h2v u = __builtin_amdgcn_cvt_pkrtz(acc[mt][2 * i], acc[mt][2 * i + 1]);
      h2v s = u * c001;
      h2v m = __builtin_elementwise_max(u, s);
      w[mt * 8 + i] = __builtin_bit_cast(uint, m);
    }
  }
#pragma unroll
  for (int kt = 0; kt < 8; ++kt) {
    int mt = kt >> 1, sub = kt & 1;
    int W = mt * 8 + sub * 4;
    uint a0 = w[W], a1 = w[W + 1], a2 = w[W + 2], a3 = w[W + 3];
    pl32swap(a0, a2);
    pl32swap(a1, a3);
    Bn[kt] = mk8(a0, a1, a2, a3);
  }
}

// perception for one active pixel from the f16 band in LDS: 9 ds_read_b128
// band slot order: half=(ch>>1)&1, j=(ch>>2)*2+(ch&1)
// byte addr = (sr*256+col)*32 + ((half ^ (col&1))<<4) + j*2
__device__ __forceinline__ void perc_band(const unsigned char* __restrict__ xband,
                                          int rl, int c, int hi, f16x8 B1h[4]) {
  const bool fL = c > 0, fR = c < NW - 1;
  const int cm = fL ? c - 1 : c, cp2 = fR ? c + 1 : c;
  const int swm = (hi ^ (cm & 1)) << 4;
  const int swc = (hi ^ (c & 1)) << 4;
  const int swp = (hi ^ (cp2 & 1)) << 4;
  union U4 { uint4 u; f16 hh[8]; };
  U4 q[9];
#pragma unroll
  for (int dr = 0; dr < 3; ++dr) {
    const unsigned char* rowp = xband + (size_t)(rl + dr) * 256 * 32;
    q[dr * 3 + 0].u = *(const uint4*)(rowp + cm * 32 + swm);
    q[dr * 3 + 1].u = *(const uint4*)(rowp + c * 32 + swc);
    q[dr * 3 + 2].u = *(const uint4*)(rowp + cp2 * 32 + swp);
  }
  uint yw[16];
#pragma unroll
  for (int j = 0; j < 8; ++j) {
    float v00 = (float)q[0].hh[j], v01 = (float)q[1].hh[j], v02 = (float)q[2].hh[j];
    float v10 = (float)q[3].hh[j], v11 = (float)q[4].hh[j], v12 = (float)q[5].hh[j];
    float v20 = (float)q[6].hh[j], v21 = (float)q[7].hh[j], v22 = (float)q[8].hh[j];
    if (!fL) { v00 = 0.f; v10 = 0.f; v20 = 0.f; }
    if (!fR) { v02 = 0.f; v12 = 0.f; v22 = 0.f; }
    float rs0 = v00 + v01 + v02, rs2 = v20 + v21 + v22;
    float fsx = (v02 - v00) + (v22 - v20) + 2.f * (v12 - v10);
    float fsy = (rs2 - rs0) + (v21 - v01);
    float flap = (rs0 + rs2 + v10 + v12) - 8.f * v11;
    h2v t0 = __builtin_amdgcn_cvt_pkrtz(v11, fsx);
    h2v t1 = __builtin_amdgcn_cvt_pkrtz(fsy, flap);
    int kt = j >> 1, cp = j & 1;
    yw[kt * 4 + cp * 2 + 0] = __builtin_bit_cast(uint, t0);
    yw[kt * 4 + cp * 2 + 1] = __builtin_bit_cast(uint, t1);
  }
#pragma unroll
  for (int kt = 0; kt < 4; ++kt)
    B1h[kt] = mk8(yw[kt * 4], yw[kt * 4 + 1], yw[kt * 4 + 2], yw[kt * 4 + 3]);
}

// Sparse band kernel: persistent 256 blocks x 768 thr; per band: stage f16 band
// via per-(sr,col,half) register packing + ONE ds_write_b128 (conflict-light),
// compact actives -> barrier -> MLP on active batches only.
__global__ __launch_bounds__(768, 1)
void nca_band_k(const float* __restrict__ x, const float* __restrict__ wsf,
                const float* __restrict__ mask, float* __restrict__ xn) {
  extern __shared__ unsigned char smem[];
  unsigned char* xband = smem + XBAND_OFF;
  ushort* list = (ushort*)(smem + LIST_OFF);
  int* ctr = (int*)(smem + CTR_OFF);

  const int tid = threadIdx.x;
  const int lane = tid & 63;
  const int wv = tid >> 6;        // 0..11
  const int hi = lane >> 5;

  // ---- stage weights+bias once ----
  {
    const uint4* src = (const uint4*)wsf;
    uint4* dst = (uint4*)smem;
    for (int i = tid; i < WS_BYTES / 16; i += 768) dst[i] = src[i];
  }
  __syncthreads();

  for (int band = blockIdx.x; band < NBANDS_TOTAL; band += 256) {
    const int b = band / NBANDS_PER_IMG;
    const int r0 = (band - b * NBANDS_PER_IMG) * BAND_ROWS;
    const float* xb = x + (size_t)b * CHW;
    float* xnb = xn + (size_t)b * CHW;
    const float* mb = mask + (size_t)b * HW;

    if (tid == 0) *ctr = 0;
    __syncthreads();

    // ---- stage band: one thread per (sr, col, half) -> single b128 write ----
    // global loads coalesced (lane <-> col); record packed in regs.
    for (int e = tid; e < STAGE_ROWS * 2 * 256; e += 768) {
      int col = e & 255;
      int pair = e >> 8;        // 0..13
      int sr = pair >> 1;
      int h = pair & 1;
      int gr = r0 - 1 + sr;
      union { f16 hh[8]; uint4 u; } rec;
      if ((unsigned)gr < (unsigned)NH) {
#pragma unroll
        for (int j = 0; j < 8; ++j) {
          int ch = ((j >> 1) << 2) | (h << 1) | (j & 1);
          rec.hh[j] = (f16)xb[((size_t)ch << 16) + (gr << 8) + col];
        }
      } else {
        rec.u.x = 0; rec.u.y = 0; rec.u.z = 0; rec.u.w = 0;
      }
      *(uint4*)(xband + (size_t)(sr * 256 + col) * 32 + ((h ^ (col & 1)) << 4)) = rec.u;
    }

    // ---- compact actives: wave w (<5) handles row r0+w ----
    if (wv < BAND_ROWS) {
      int row = r0 + wv;
      if (row < NH) {
        ull bal[4];
        int c = 0;
#pragma unroll
        for (int k = 0; k < 4; ++k) {
          bool a = mb[(row << 8) + k * 64 + lane] > 0.f;
          bal[k] = __ballot(a);
          c += __popcll(bal[k]);
        }
        int base;
        if (lane == 0) base = atomicAdd(ctr, c);
        base = __shfl(base, 0);
#pragma unroll
        for (int k = 0; k < 4; ++k) {
          int rank = __popcll(bal[k] & ((1ull << lane) - 1));
          if ((bal[k] >> lane) & 1ull)
            list[base + rank] = (ushort)((wv << 8) | (k * 64 + lane));
          base += __popcll(bal[k]);
        }
      }
    }
    __syncthreads();

    // ---- MLP on active batches ----
    const int n = *ctr;
    const int nbatch = (n + 31) >> 5;
    for (int k = wv; k < nbatch; k += 12) {
      int idx = k * 32 + (lane & 31);
      if (idx >= n) idx = n - 1;
      const int entry = list[idx];
      const int rl = entry >> 8, c = entry & 255;

      f16x8 B1[4];
      perc_band(xband, rl, c, hi, B1);

      f32x16 acc[4];
      f16x8 B2[8], B3[8], B4[8];
      gemm_half<4>(smem, 0, 0, lane, hi, B1, acc);
      epilogue_swap(acc, B2);
      gemm_half<8>(smem, 1024, 128, lane, hi, B2, acc);
      epilogue_swap(acc, B3);
      gemm_half<8>(smem, 3072, 256, lane, hi, B3, acc);
      epilogue_swap(acc, B4);

      f32x16 a4;
#pragma unroll
      for (int r = 0; r < 16; ++r) a4[r] = 0.f;
      {
        const f16x8* A4 = (const f16x8*)smem + 5120 + lane;
        __builtin_amdgcn_s_setprio(1);
#pragma unroll
        for (int kt = 0; kt < 8; ++kt)
          a4 = __builtin_amdgcn_mfma_f32_32x32x16_f16(A4[kt * 64], B4[kt], a4, 0, 0, 0);
        __builtin_amdgcn_s_setprio(0);
      }

      // update active px: mask==1 -> x + dy (exact f32 x re-read)
      {
        const int row = r0 + rl;
        const float* xrb = xb + (row << 8) + c;
        float* xob = xnb + (row << 8) + c;
#pragma unroll
        for (int r = 0; r < 8; ++r) {
          int ch = (r & 3) + 8 * (r >> 2) + 4 * hi;
          xob[(size_t)ch << 16] = xrb[(size_t)ch << 16] + a4[r];
        }
      }
    }
    __syncthreads();   // band LDS free for next iteration
  }
}

// alive factor: row-block with LDS horizontal-max sharing; zero dead pixels
__global__ void alive_scale_k(const float* __restrict__ x, float* __restrict__ xn) {
  __shared__ float pm[4][258];
  const int col = threadIdx.x;
  const int row = blockIdx.x;
  const int b = blockIdx.y;
  const float NEG = -3.0e38f;
  float v0 = NEG, v1 = NEG, v2 = NEG, v3 = NEG;
  const size_t base0 = (size_t)b * CHW + ((size_t)row << 8) + col;
#pragma unroll
  for (int dr = -1; dr <= 1; ++dr) {
    int rr = row + dr;
    if ((unsigned)rr < NH) {
      long o = (long)base0 + dr * NW;
      v0 = fmaxf(v0, x[o]);
      v1 = fmaxf(v1, x[o + HW]);
      v2 = fmaxf(v2, xn[o]);
      v3 = fmaxf(v3, xn[o + HW]);
    }
  }
  pm[0][col + 1] = v0;
  pm[1][col + 1] = v1;
  pm[2][col + 1] = v2;
  pm[3][col + 1] = v3;
  if (col == 0) {
#pragma unroll
    for (int f = 0; f < 4; ++f) { pm[f][0] = NEG; pm[f][257] = NEG; }
  }
  __syncthreads();
  float p0 = fmaxf(fmaxf(pm[0][col], pm[0][col + 1]), pm[0][col + 2]);
  float p1 = fmaxf(fmaxf(pm[1][col], pm[1][col + 1]), pm[1][col + 2]);
  float p2 = fmaxf(fmaxf(pm[2][col], pm[2][col + 1]), pm[2][col + 2]);
  float p3 = fmaxf(fmaxf(pm[3][col], pm[3][col + 1]), pm[3][col + 2]);
  bool alive = ((fabsf(p0) + fabsf(p1)) > 0.01f) && ((fabsf(p2) + fabsf(p3)) > 0.01f);
  if (!alive) {
#pragma unroll
    for (int ch = 0; ch < NCH; ++ch) xn[base0 + ((size_t)ch << 16)] = 0.f;
  }
}

extern "C" void kernel_launch(void* const* d_in, const int* in_sizes, int n_in,
                              void* d_out, int out_size, void* d_ws, size_t ws_size,
                              hipStream_t stream) {
  const float* x    = (const float*)d_in[0];
  const float* w1   = (const float*)d_in[1];
  const float* b1   = (const float*)d_in[2];
  const float* w2   = (const float*)d_in[3];
  const float* b2   = (const float*)d_in[4];
  const float* w3   = (const float*)d_in[5];
  const float* b3   = (const float*)d_in[6];
  const float* w4   = (const float*)d_in[7];
  const float* mask = (const float*)d_in[8];

  float* wsf = (float*)d_ws;
  float* xn = (float*)d_out;

  hipFuncSetAttribute(reinterpret_cast<const void*>(nca_band_k),
                      hipFuncAttributeMaxDynamicSharedMemorySize, LDS_TOTAL);

  prep_k<<<178, 256, 0, stream>>>(w1, w2, w3, w4, b1, b2, b3, wsf);
  copy_k<<<2048, 256, 0, stream>>>((const float4*)x, (float4*)xn);
  nca_band_k<<<256, 768, LDS_TOTAL, stream>>>(x, wsf, mask, xn);
  alive_scale_k<<<dim3(NH, NB), 256, 0, stream>>>(x, xn);
}